// Round 1
// baseline (1402.647 us; speedup 1.0000x reference)
//
#include <hip/hip_runtime.h>
#include <hip/hip_bf16.h>

// Problem constants (from reference)
#define B_SZ 2048
#define K_SZ 8
#define O_SZ 256
#define I_SZ 512
#define TINY 1e-10f

// ---------------------------------------------------------------------------
// Kernel 1: per-batch gumbel-softmax hard argmax.
// logits[b,k] = mix_weights[k]; g = -log(-log(u+TINY)+TINY); tau=1.
// argmax over k of (logits+g) == argmax of softmax (monotone). '>' keeps the
// first max, matching jnp.argmax tie-break.
// ---------------------------------------------------------------------------
__global__ void gumbel_argmax_kernel(const float* __restrict__ mixw,
                                     const float* __restrict__ u,
                                     int* __restrict__ kidx) {
    int b = blockIdx.x * blockDim.x + threadIdx.x;
    if (b >= B_SZ) return;
    float best = -INFINITY;
    int   bi   = 0;
#pragma unroll
    for (int k = 0; k < K_SZ; ++k) {
        float uu = u[b * K_SZ + k];
        float g  = -__logf(-__logf(uu + TINY) + TINY);
        // use precise logf for exact match with reference numerics
        g = -logf(-logf(uu + TINY) + TINY);
        float z = mixw[k] + g;   // tau == 1
        if (z > best) { best = z; bi = k; }
    }
    kidx[b] = bi;
}

// ---------------------------------------------------------------------------
// Kernel 2: sigma = exp(log_sigma), K*O*I = 1M elements, float4 per thread.
// ---------------------------------------------------------------------------
__global__ void exp_kernel(const float* __restrict__ ls, float* __restrict__ sg) {
    int i = blockIdx.x * blockDim.x + threadIdx.x;   // float4 index
    float4 v = ((const float4*)ls)[i];
    float4 r;
    r.x = expf(v.x); r.y = expf(v.y); r.z = expf(v.z); r.w = expf(v.w);
    ((float4*)sg)[i] = r;
}

// ---------------------------------------------------------------------------
// Kernel 3: main batched matvec. One wave per output element (b,o).
// out[b,o] = sum_i X[b,i] * (mean[k,o,i] + sigma[k,o,i]*eps[b,o,i])
// 4 waves/block; lane reads 2x float4 per stream (coalesced 16B/lane).
// SIGMA_PRE: sigma precomputed in ws. KIDX_PRE: kidx precomputed in ws.
// ---------------------------------------------------------------------------
template <bool SIGMA_PRE, bool KIDX_PRE>
__global__ __launch_bounds__(256) void blm_main_kernel(
    const float* __restrict__ X,
    const float* __restrict__ mean,
    const float* __restrict__ sig_or_ls,   // sigma (pre) or log_sigma (inline)
    const float* __restrict__ eps,
    const int*   __restrict__ kidx,        // valid iff KIDX_PRE
    const float* __restrict__ mixw,        // used iff !KIDX_PRE
    const float* __restrict__ u,           // used iff !KIDX_PRE
    float* __restrict__ out) {
    const int wave = threadIdx.x >> 6;
    const int lane = threadIdx.x & 63;
    const int out_idx = blockIdx.x * 4 + wave;   // [0, B*O)
    const int b = out_idx >> 8;                  // O = 256
    const int o = out_idx & 255;

    int k;
    if (KIDX_PRE) {
        k = kidx[b];
    } else {
        // lanes 0..7 each evaluate one gumbel; argmax-reduce over 8 lanes
        float val = -INFINITY;
        int   idx = lane;
        if (lane < K_SZ) {
            float uu = u[b * K_SZ + lane];
            float g  = -logf(-logf(uu + TINY) + TINY);
            val = mixw[lane] + g;
        }
#pragma unroll
        for (int m = 1; m < K_SZ; m <<= 1) {
            float oval = __shfl_xor(val, m);
            int   oidx = __shfl_xor(idx, m);
            if (oval > val || (oval == val && oidx < idx)) { val = oval; idx = oidx; }
        }
        k = __shfl(idx, 0);
    }

    const float4* Xv = (const float4*)(X + (size_t)b * I_SZ);
    const float4* Ev = (const float4*)(eps + (size_t)out_idx * I_SZ);
    const float4* Mv = (const float4*)(mean + ((size_t)k * O_SZ + o) * I_SZ);
    const float4* Sv = (const float4*)(sig_or_ls + ((size_t)k * O_SZ + o) * I_SZ);

    float acc = 0.f;
#pragma unroll
    for (int p = 0; p < I_SZ / 4 / 64; ++p) {    // 2 iterations
        const int idx = p * 64 + lane;
        float4 x = Xv[idx];
        float4 e = Ev[idx];
        float4 m = Mv[idx];
        float4 s = Sv[idx];
        if (!SIGMA_PRE) {
            s.x = expf(s.x); s.y = expf(s.y); s.z = expf(s.z); s.w = expf(s.w);
        }
        acc += x.x * fmaf(s.x, e.x, m.x);
        acc += x.y * fmaf(s.y, e.y, m.y);
        acc += x.z * fmaf(s.z, e.z, m.z);
        acc += x.w * fmaf(s.w, e.w, m.w);
    }
#pragma unroll
    for (int off = 32; off; off >>= 1) acc += __shfl_down(acc, off);
    if (lane == 0) out[out_idx] = acc;
}

extern "C" void kernel_launch(void* const* d_in, const int* in_sizes, int n_in,
                              void* d_out, int out_size, void* d_ws, size_t ws_size,
                              hipStream_t stream) {
    const float* X    = (const float*)d_in[0];
    const float* mixw = (const float*)d_in[1];
    const float* mean = (const float*)d_in[2];
    const float* ls   = (const float*)d_in[3];
    const float* u    = (const float*)d_in[4];
    const float* eps  = (const float*)d_in[5];
    float* out = (float*)d_out;

    const size_t kidx_bytes  = B_SZ * sizeof(int);                 // 8 KB
    const size_t sigma_bytes = (size_t)K_SZ * O_SZ * I_SZ * 4;     // 4 MB
    const bool have_kidx  = ws_size >= kidx_bytes;
    const bool have_sigma = ws_size >= kidx_bytes + sigma_bytes;

    int*   kidx  = (int*)d_ws;
    float* sigma = (float*)((char*)d_ws + kidx_bytes);

    const int nblk = (B_SZ * O_SZ) / 4;   // 131072 blocks, 4 waves each

    if (have_kidx) {
        gumbel_argmax_kernel<<<(B_SZ + 255) / 256, 256, 0, stream>>>(mixw, u, kidx);
        if (have_sigma) {
            exp_kernel<<<(K_SZ * O_SZ * I_SZ / 4 + 255) / 256, 256, 0, stream>>>(ls, sigma);
            blm_main_kernel<true, true><<<nblk, 256, 0, stream>>>(
                X, mean, sigma, eps, kidx, mixw, u, out);
        } else {
            blm_main_kernel<false, true><<<nblk, 256, 0, stream>>>(
                X, mean, ls, eps, kidx, mixw, u, out);
        }
    } else {
        blm_main_kernel<false, false><<<nblk, 256, 0, stream>>>(
            X, mean, ls, eps, kidx, mixw, u, out);
    }
}